// Round 3
// baseline (38.155 us; speedup 1.0000x reference)
//
#include <hip/hip_runtime.h>

// MaxUnpool2D: in [16,64,64,128] f32, mask [16,64,64,128] i32 (flat NHWC index
// with Ho=128, Wo=128, guaranteed inside the 2x2 window of each input elem),
// out [16,128,128,128] f32.
//
// No scatter collisions (windows partition the output; channel preserved), so
// each thread owns one input float4 and writes the full 2x2 window for its 4
// channels: selected slot = value, others = 0. Single pass, output fully
// initialized every call.
//
// R3: nontemporal via clang ext_vector_type (HIP_vector_type structs are
// rejected by __builtin_nontemporal_*).

typedef float f32x4 __attribute__((ext_vector_type(4)));
typedef int   i32x4 __attribute__((ext_vector_type(4)));

__global__ __launch_bounds__(256) void MaxUnpool2D_59047210385945_kernel(
    const f32x4* __restrict__ in, const i32x4* __restrict__ mask,
    f32x4* __restrict__ out, int n4) {
    int i = blockIdx.x * blockDim.x + threadIdx.x;
    if (i >= n4) return;

    // i indexes float4 groups: c4 = i & 31 (C/4 = 32), w = (i>>5)&63,
    // h = (i>>11)&63, b = i>>17.
    int c4 = i & 31;
    int w  = (i >> 5) & 63;
    int h  = (i >> 11) & 63;
    int b  = i >> 17;

    f32x4 v = __builtin_nontemporal_load(&in[i]);
    i32x4 m = __builtin_nontemporal_load(&mask[i]);

    f32x4 o00, o01, o10, o11;

    // Per-channel slot decode: dh = bit14 of mask, dw = bit7 of mask.
    #pragma unroll
    for (int k = 0; k < 4; ++k) {
        int dh = (m[k] >> 14) & 1, dw = (m[k] >> 7) & 1;
        float val = v[k];
        o00[k] = (dh == 0 && dw == 0) ? val : 0.0f;
        o01[k] = (dh == 0 && dw == 1) ? val : 0.0f;
        o10[k] = (dh == 1 && dw == 0) ? val : 0.0f;
        o11[k] = (dh == 1 && dw == 1) ? val : 0.0f;
    }

    // Output base in float4 units: ((b*128 + 2h)*128 + 2w)*128 floats + c4*4
    // -> /4: (((b*128 + 2h)*128 + 2w) << 5) + c4.
    int base = ((((b << 7) + 2 * h) << 7) + 2 * w);
    base = (base << 5) + c4;

    __builtin_nontemporal_store(o00, &out[base]);              // (2h,   2w  )
    __builtin_nontemporal_store(o01, &out[base + 32]);         // (2h,   2w+1)
    __builtin_nontemporal_store(o10, &out[base + 4096]);       // (2h+1, 2w  )
    __builtin_nontemporal_store(o11, &out[base + 4096 + 32]);  // (2h+1, 2w+1)
}

extern "C" void kernel_launch(void* const* d_in, const int* in_sizes, int n_in,
                              void* d_out, int out_size, void* d_ws, size_t ws_size,
                              hipStream_t stream) {
    const f32x4* in   = (const f32x4*)d_in[0];
    const i32x4* mask = (const i32x4*)d_in[1];
    f32x4*       out  = (f32x4*)d_out;

    int n4 = in_sizes[0] / 4;  // 16*64*64*128 / 4 = 2,097,152
    int threads = 256;
    int blocks = (n4 + threads - 1) / threads;
    MaxUnpool2D_59047210385945_kernel<<<blocks, threads, 0, stream>>>(in, mask, out, n4);
}

// Round 4
// 33.812 us; speedup vs baseline: 1.1284x; 1.1284x over previous
//
#include <hip/hip_runtime.h>

// MaxUnpool2D: in [16,64,64,128] f32, mask [16,64,64,128] i32 (flat NHWC index
// with Ho=128, Wo=128, guaranteed inside the 2x2 window of each input elem),
// out [16,128,128,128] f32.
//
// R4: output-centric GATHER. Each thread owns one OUTPUT float4 (b,ho,wo,c4),
// reads the corresponding input/mask float4 at (b,ho/2,wo/2,c4), and writes
// value-or-zero depending on whether the mask selects (ho&1, wo&1). Writes are
// perfectly contiguous (1 KB per wave-instruction, like the 7 TB/s fill
// kernel); the 4x read reuse stays in-block:
//   block = 256 thr = [dh:1][wl:2][c4:5] covering 2 output rows x 4 wo x 128 c.
//   lanes 0-31 / 32-63 of a wave = (dw=0, dw=1) of the SAME input line;
//   dh=0 waves (0,1) and dh=1 waves (2,3) re-read the same 4 KB via L1.
// No NT: R3 showed nt bypassing L2 defeats write-combining (-10%).

typedef float f32x4 __attribute__((ext_vector_type(4)));
typedef int   i32x4 __attribute__((ext_vector_type(4)));

__global__ __launch_bounds__(256) void MaxUnpool2D_59047210385945_kernel(
    const f32x4* __restrict__ in, const i32x4* __restrict__ mask,
    f32x4* __restrict__ out) {
    // Grid: 16(b) x 64(h) x 32(wc) = 32768 blocks.
    int bid = blockIdx.x;
    int wc = bid & 31;          // 4-wo chunk
    int h  = (bid >> 5) & 63;   // input row
    int b  = bid >> 11;

    int tid = threadIdx.x;
    int c4 = tid & 31;          // float4 channel group (C/4 = 32)
    int wl = (tid >> 5) & 3;    // wo within chunk
    int dh = tid >> 7;          // output row parity

    int wo = (wc << 2) + wl;
    int w  = wo >> 1;
    int dw = wo & 1;
    int ho = (h << 1) + dh;

    // input float4 index: ((b*64 + h)*64 + w)*32 + c4
    int iin = ((((b << 6) + h) << 6) + w);
    iin = (iin << 5) + c4;

    f32x4 v = in[iin];
    i32x4 m = mask[iin];

    f32x4 o;
    #pragma unroll
    for (int k = 0; k < 4; ++k) {
        // selected slot: bit14 of mask = dh, bit7 = dw
        int sel_dh = (m[k] >> 14) & 1;
        int sel_dw = (m[k] >> 7) & 1;
        o[k] = (sel_dh == dh && sel_dw == dw) ? v[k] : 0.0f;
    }

    // output float4 index: ((b*128 + ho)*128 + wo)*32 + c4
    int iout = ((((b << 7) + ho) << 7) + wo);
    iout = (iout << 5) + c4;

    out[iout] = o;
}

extern "C" void kernel_launch(void* const* d_in, const int* in_sizes, int n_in,
                              void* d_out, int out_size, void* d_ws, size_t ws_size,
                              hipStream_t stream) {
    const f32x4* in   = (const f32x4*)d_in[0];
    const i32x4* mask = (const i32x4*)d_in[1];
    f32x4*       out  = (f32x4*)d_out;

    // 16*64*32 = 32768 blocks x 256 threads = 8,388,608 threads = out float4s
    MaxUnpool2D_59047210385945_kernel<<<32768, 256, 0, stream>>>(in, mask, out);
}